// Round 3
// baseline (458.593 us; speedup 1.0000x reference)
//
#include <hip/hip_runtime.h>

// No hip_bf16.h: hand-rolled bf16<->f32 to minimize compile-failure surface.
#ifndef __has_builtin
#define __has_builtin(x) 0
#endif
#if __has_builtin(__builtin_amdgcn_mfma_f32_16x16x32_bf16)
#define HAVE_MFMA 1
#else
#define HAVE_MFMA 0
#endif

using bf16x8 = __attribute__((ext_vector_type(8))) short;  // guide-verified frag type
using f32x4  = __attribute__((ext_vector_type(4))) float;
typedef unsigned short u16;
typedef unsigned int u32;

#define BN 2048
#define DD 128
#define EE 64
#define HH 256

__device__ __forceinline__ float bf2f(u16 u) {
  union { u32 i; float f; } c; c.i = ((u32)u) << 16; return c.f;
}
__device__ __forceinline__ u16 f2bf(float f) {  // RNE
  union { float f; u32 i; } c; c.f = f;
  u32 x = c.i; u32 r = x + 0x7FFFu + ((x >> 16) & 1u);
  return (u16)(r >> 16);
}
__device__ __forceinline__ float ldT(const float* p, int i) { return p[i]; }
__device__ __forceinline__ float ldT(const u16* p, int i) { return bf2f(p[i]); }

// swizzled LDS addressing (16B chunks xor'ed by row&7)
__device__ __forceinline__ int swz(int row, int e) {
  int c = e >> 3, r = e & 7;
  return row * 64 + (((c ^ (row & 7)) << 3) | r);
}

// stage 8 source elems -> 8 bf16 shorts at 16B-aligned LDS dst
__device__ __forceinline__ void stage8(const u16* s, u16* d) {
  *(float4*)d = *(const float4*)s;
}
__device__ __forceinline__ void stage8(const float* s, u16* d) {
  float4 a = *(const float4*)s, b = *(const float4*)(s + 4);
  d[0]=f2bf(a.x); d[1]=f2bf(a.y); d[2]=f2bf(a.z); d[3]=f2bf(a.w);
  d[4]=f2bf(b.x); d[5]=f2bf(b.y); d[6]=f2bf(b.z); d[7]=f2bf(b.w);
}

// ---------------------------------------------------------------------------
// detect dtype of inputs + write canary 1.0 to out.
// fp32 storage: low 16 bits of each word = random mantissa -> ~12% "sane" exp.
// bf16 storage: every u16 is a bf16 of N(0,1) -> ~100% sane exponents.
// ---------------------------------------------------------------------------
__global__ __launch_bounds__(256) void k_detect(const u16* __restrict__ nodes_u16,
                                                int* __restrict__ flag,
                                                void* __restrict__ out, int out_n) {
  __shared__ int cnt;
  __shared__ int fl;
  const int t = threadIdx.x;
  if (t == 0) cnt = 0;
  __syncthreads();
  u16 v = nodes_u16[t * 1024];           // even indices, < 262144 (bf16-size safe)
  int e = (v >> 7) & 0xFF;
  atomicAdd(&cnt, (e >= 0x70 && e <= 0x8F) ? 1 : 0);
  __syncthreads();
  if (t == 0) { fl = (cnt >= 128) ? 1 : 0; *flag = fl; }
  __syncthreads();
  if (fl) {
    u16* o = (u16*)out;
    for (int i = t; i < out_n; i += 256) o[i] = 0x3F80;  // bf16 1.0
  } else {
    float* o = (float*)out;
    for (int i = t; i < out_n; i += 256) o[i] = 1.0f;
  }
}

// ---------------------------------------------------------------------------
// canonicalize all 14 weight tensors to fp32 in ws (runs only if *flag==WANT)
// ---------------------------------------------------------------------------
struct WPtrs { const void* p[14]; };

template <typename T>
__global__ __launch_bounds__(256) void k_cvtw(WPtrs wp, const int* __restrict__ flag,
                                              float* __restrict__ canon, int want) {
  if (*flag != want) return;
  const int lens[14] = {147456, 768, 196608, 768, 294912, 768, 98304, 384,
                        384, 384, 32768, 256, 32768, 128};
  const int gid = blockIdx.x * 256 + threadIdx.x;
  const int gsz = gridDim.x * 256;
  int off = 0;
  for (int s = 0; s < 14; s++) {
    const T* src = (const T*)wp.p[s];
    float* dst = canon + off;
    for (int i = gid; i < lens[s]; i += gsz) dst[i] = ldT(src, i);
    off += lens[s];
  }
}

template <typename T>
__global__ __launch_bounds__(256) void k_cvtn(const T* __restrict__ nodes,
                                              const int* __restrict__ flag,
                                              float* __restrict__ xbuf, int want) {
  if (*flag != want) return;
  const int gid = blockIdx.x * 256 + threadIdx.x;
  const int gsz = gridDim.x * 256;
  for (int i = gid; i < BN * DD; i += gsz) xbuf[i] = ldT(nodes, i);
}

// ---------------------------------------------------------------------------
// per (b,i): hsum[bi][h] = sum_j relu( npart[h] + edges[bi][j][:] @ W1e[:,h] )
// npart[h] = x[bi] @ W1a[:,h] + b1[h].  MFMA 16x16x32 bf16 (VALU fallback).
// ---------------------------------------------------------------------------
template <typename T>
__global__ __launch_bounds__(256) void k_edge(
    const T* __restrict__ edges, const int* __restrict__ flag, int want,
    const float* __restrict__ xbuf,
    const float* __restrict__ w1C,   // layer base of msg_w1 canon [192][256]
    const float* __restrict__ b1C,   // [256]
    float* __restrict__ hsum) {
  if (*flag != want) return;
  __shared__ __align__(16) u16 eL[128 * 64];
  __shared__ __align__(16) u16 wL[256 * 64];
  __shared__ float npL[256];

  const int bi = blockIdx.x;
  const int t = threadIdx.x;

  // stage edges tile (128 x 64) -> bf16 LDS, swizzled
  const T* eg = edges + (size_t)bi * (128 * 64);
  #pragma unroll
  for (int q = 0; q < 4; q++) {
    int idx = q * 256 + t;
    int j = idx >> 3, c = idx & 7;
    stage8(eg + j * 64 + c * 8, &eL[j * 64 + ((c ^ (j & 7)) * 8)]);
  }
  // stage W1e^T (h-major) -> bf16 LDS, swizzled; src = w1C rows 128..191 (fp32)
  {
    const float* we = w1C + 128 * 256;  // we[e*256 + h]
    #pragma unroll
    for (int c = 0; c < 8; c++) {
      u16 tmp[8];
      #pragma unroll
      for (int j = 0; j < 8; j++) tmp[j] = f2bf(we[(c * 8 + j) * 256 + t]);
      *(float4*)(&wL[t * 64 + ((c ^ (t & 7)) * 8)]) = *(const float4*)tmp;
    }
  }
  // node part
  {
    const float* xr = xbuf + (size_t)bi * DD;
    float acc = b1C[t];
    #pragma unroll 8
    for (int k = 0; k < DD; k++) acc = fmaf(xr[k], w1C[k * 256 + t], acc);
    npL[t] = acc;
  }
  __syncthreads();

#if HAVE_MFMA
  const int lane = t & 63;
  const int w = t >> 6;
  const int lr = lane & 15;
  const int quad = lane >> 4;

  bf16x8 afr[8][2];
  #pragma unroll
  for (int jt = 0; jt < 8; jt++) {
    int m = jt * 16 + lr;
    #pragma unroll
    for (int kc = 0; kc < 2; kc++) {
      int c8 = kc * 4 + quad;
      afr[jt][kc] = *(const bf16x8*)(&eL[m * 64 + ((c8 ^ (m & 7)) * 8)]);
    }
  }
  float* hrow = hsum + (size_t)bi * HH;
  #pragma unroll
  for (int ht = 0; ht < 4; ht++) {
    const int n = w * 64 + ht * 16 + lr;
    bf16x8 bf0 = *(const bf16x8*)(&wL[n * 64 + (((0 + quad) ^ (n & 7)) * 8)]);
    bf16x8 bf1 = *(const bf16x8*)(&wL[n * 64 + (((4 + quad) ^ (n & 7)) * 8)]);
    const float npv = npL[n];
    float colsum = 0.f;
    #pragma unroll
    for (int jt = 0; jt < 8; jt++) {
      f32x4 acc = {0.f, 0.f, 0.f, 0.f};
      acc = __builtin_amdgcn_mfma_f32_16x16x32_bf16(afr[jt][0], bf0, acc, 0, 0, 0);
      acc = __builtin_amdgcn_mfma_f32_16x16x32_bf16(afr[jt][1], bf1, acc, 0, 0, 0);
      #pragma unroll
      for (int r = 0; r < 4; r++) colsum += fmaxf(acc[r] + npv, 0.f);
    }
    colsum += __shfl_xor(colsum, 16);
    colsum += __shfl_xor(colsum, 32);
    if (quad == 0) hrow[n] = colsum;
  }
#else
  // VALU fallback (slow, correctness only): thread t owns column h=t
  float hs = 0.f;
  for (int j = 0; j < 128; j++) {
    float p = npL[t];
    for (int e = 0; e < 64; e++)
      p = fmaf(bf2f(eL[swz(j, e)]), bf2f(wL[swz(t, e)]), p);
    hs += fmaxf(p, 0.f);
  }
  hsum[(size_t)bi * HH + t] = hs;
#endif
}

// ---------------------------------------------------------------------------
// per 8 rows: agg = hsum@w2 + 128*b2; u = relu([x,agg]@uw1+ub1)@uw2+ub2;
// y = x+u; layernorm -> xbuf (fp32, in-place safe: rows private to block)
// ---------------------------------------------------------------------------
__global__ __launch_bounds__(256) void k_update(
    float* __restrict__ xbuf, const float* __restrict__ hsum,
    const float* __restrict__ w2C, const float* __restrict__ b2C,
    const float* __restrict__ uw1C, const float* __restrict__ ub1C,
    const float* __restrict__ uw2C, const float* __restrict__ ub2C,
    const float* __restrict__ lngC, const float* __restrict__ lnbC) {
  __shared__ float xl[8 * 128];
  __shared__ float hl[8 * 256];
  __shared__ float al[8 * 256];
  __shared__ float u1l[8 * 256];
  __shared__ float yl[8 * 128];

  const int t = threadIdx.x;
  const int r0 = blockIdx.x * 8;

  #pragma unroll
  for (int q = 0; q < 4; q++) xl[q * 256 + t] = xbuf[(size_t)r0 * 128 + q * 256 + t];
  #pragma unroll
  for (int q = 0; q < 2; q++) {
    int f = q * 256 + t;
    *(float4*)(&hl[f * 4]) = *(const float4*)(hsum + (size_t)r0 * 256 + f * 4);
  }
  __syncthreads();

  {
    float acc[8] = {0, 0, 0, 0, 0, 0, 0, 0};
    for (int k = 0; k < 256; k++) {
      float wv = w2C[k * 256 + t];
      #pragma unroll
      for (int r = 0; r < 8; r++) acc[r] = fmaf(hl[r * 256 + k], wv, acc[r]);
    }
    float bv = 128.f * b2C[t];
    #pragma unroll
    for (int r = 0; r < 8; r++) al[r * 256 + t] = acc[r] + bv;
  }
  __syncthreads();

  {
    float acc[8] = {0, 0, 0, 0, 0, 0, 0, 0};
    for (int k = 0; k < 128; k++) {
      float wv = uw1C[k * 256 + t];
      #pragma unroll
      for (int r = 0; r < 8; r++) acc[r] = fmaf(xl[r * 128 + k], wv, acc[r]);
    }
    for (int k = 0; k < 256; k++) {
      float wv = uw1C[(128 + k) * 256 + t];
      #pragma unroll
      for (int r = 0; r < 8; r++) acc[r] = fmaf(al[r * 256 + k], wv, acc[r]);
    }
    float bv = ub1C[t];
    #pragma unroll
    for (int r = 0; r < 8; r++) u1l[r * 256 + t] = fmaxf(acc[r] + bv, 0.f);
  }
  __syncthreads();

  {
    const int d = t & 127;
    const int half = t >> 7;
    float acc[4] = {0, 0, 0, 0};
    for (int k = 0; k < 256; k++) {
      float wv = uw2C[k * 128 + d];
      #pragma unroll
      for (int rr = 0; rr < 4; rr++)
        acc[rr] = fmaf(u1l[(half * 4 + rr) * 256 + k], wv, acc[rr]);
    }
    float bv = ub2C[d];
    #pragma unroll
    for (int rr = 0; rr < 4; rr++) {
      int r = half * 4 + rr;
      yl[r * 128 + d] = xl[r * 128 + d] + acc[rr] + bv;
    }
  }
  __syncthreads();

  {
    const int r = t >> 5;
    const int c = (t & 31) * 4;
    float4 y4 = *(const float4*)(&yl[r * 128 + c]);
    float s = y4.x + y4.y + y4.z + y4.w;
    float ss = y4.x * y4.x + y4.y * y4.y + y4.z * y4.z + y4.w * y4.w;
    #pragma unroll
    for (int m = 1; m < 32; m <<= 1) { s += __shfl_xor(s, m); ss += __shfl_xor(ss, m); }
    float mean = s * (1.f / 128.f);
    float var = ss * (1.f / 128.f) - mean * mean;
    float rs = rsqrtf(var + 1e-5f);
    float* xo = xbuf + (size_t)(r0 + r) * 128;
    float yv[4] = {y4.x, y4.y, y4.z, y4.w};
    #pragma unroll
    for (int q = 0; q < 4; q++) {
      int d = c + q;
      xo[d] = (yv[q] - mean) * rs * lngC[d] + lnbC[d];
    }
  }
}

// ---------------------------------------------------------------------------
// out = relu(x@ow1 + ob1)@ow2 + ob2, written in flag dtype
// ---------------------------------------------------------------------------
__global__ __launch_bounds__(256) void k_out(
    const float* __restrict__ xbuf, const float* __restrict__ ow1C,
    const float* __restrict__ ob1C, const float* __restrict__ ow2C,
    const float* __restrict__ ob2C, const int* __restrict__ flag,
    void* __restrict__ out) {
  __shared__ float xl[8 * 128];
  __shared__ float u1l[8 * 256];
  const int t = threadIdx.x;
  const int r0 = blockIdx.x * 8;
  const int fl = *flag;
  #pragma unroll
  for (int q = 0; q < 4; q++) xl[q * 256 + t] = xbuf[(size_t)r0 * 128 + q * 256 + t];
  __syncthreads();
  {
    float acc[8] = {0, 0, 0, 0, 0, 0, 0, 0};
    for (int k = 0; k < 128; k++) {
      float wv = ow1C[k * 256 + t];
      #pragma unroll
      for (int r = 0; r < 8; r++) acc[r] = fmaf(xl[r * 128 + k], wv, acc[r]);
    }
    float bv = ob1C[t];
    #pragma unroll
    for (int r = 0; r < 8; r++) u1l[r * 256 + t] = fmaxf(acc[r] + bv, 0.f);
  }
  __syncthreads();
  {
    const int d = t & 127;
    const int half = t >> 7;
    float acc[4] = {0, 0, 0, 0};
    for (int k = 0; k < 256; k++) {
      float wv = ow2C[k * 128 + d];
      #pragma unroll
      for (int rr = 0; rr < 4; rr++)
        acc[rr] = fmaf(u1l[(half * 4 + rr) * 256 + k], wv, acc[rr]);
    }
    float bv = ob2C[d];
    #pragma unroll
    for (int rr = 0; rr < 4; rr++) {
      int r = half * 4 + rr;
      float v = acc[rr] + bv;
      size_t o = (size_t)(r0 + r) * 128 + d;
      if (fl) ((u16*)out)[o] = f2bf(v);
      else ((float*)out)[o] = v;
    }
  }
}

extern "C" void kernel_launch(void* const* d_in, const int* in_sizes, int n_in,
                              void* d_out, int out_size, void* d_ws,
                              size_t ws_size, hipStream_t stream) {
  // mask (input 2) may or may not be passed; detect by its size (2048 vs 147456)
  const int wb = (n_in >= 17 && in_sizes[2] == 2048) ? 3 : 2;

  char* ws = (char*)d_ws;
  int* flag    = (int*)ws;                         // @0
  float* xbuf  = (float*)(ws + 4096);              // 1 MB
  float* hsum  = (float*)(ws + 4096 + 1048576);    // 2 MB
  float* canon = (float*)(ws + 4096 + 1048576 + 2097152);  // 3.23 MB

  WPtrs wp;
  for (int i = 0; i < 14; i++) wp.p[i] = d_in[wb + i];

  // canon float offsets
  const int MW1 = 0, MB1 = 147456, MW2 = 148224, MB2 = 344832, UW1 = 345600,
            UB1 = 640512, UW2 = 641280, UB2 = 739584, LNG = 739968,
            LNB = 740352, OW1 = 740736, OB1 = 773504, OW2 = 773760,
            OB2 = 806528;

  k_detect<<<1, 256, 0, stream>>>((const u16*)d_in[0], flag, d_out, out_size);
  k_cvtw<float><<<512, 256, 0, stream>>>(wp, flag, canon, 0);
  k_cvtw<u16><<<512, 256, 0, stream>>>(wp, flag, canon, 1);
  k_cvtn<float><<<256, 256, 0, stream>>>((const float*)d_in[0], flag, xbuf, 0);
  k_cvtn<u16><<<256, 256, 0, stream>>>((const u16*)d_in[0], flag, xbuf, 1);

  for (int l = 0; l < 3; l++) {
    const float* w1C = canon + MW1 + l * 49152;
    const float* b1C = canon + MB1 + l * 256;
    k_edge<float><<<BN, 256, 0, stream>>>((const float*)d_in[1], flag, 0, xbuf,
                                          w1C, b1C, hsum);
    k_edge<u16><<<BN, 256, 0, stream>>>((const u16*)d_in[1], flag, 1, xbuf,
                                        w1C, b1C, hsum);
    k_update<<<BN / 8, 256, 0, stream>>>(
        xbuf, hsum, canon + MW2 + l * 65536, canon + MB2 + l * 256,
        canon + UW1 + l * 98304, canon + UB1 + l * 256,
        canon + UW2 + l * 32768, canon + UB2 + l * 128,
        canon + LNG + l * 128, canon + LNB + l * 128);
  }
  k_out<<<BN / 8, 256, 0, stream>>>(xbuf, canon + OW1, canon + OB1,
                                    canon + OW2, canon + OB2, flag, d_out);
}

// Round 6
// 387.303 us; speedup vs baseline: 1.1841x; 1.1841x over previous
//
#include <hip/hip_runtime.h>

// No hip_bf16.h: hand-rolled bf16<->f32 to minimize compile-failure surface.
// Guard kept EXACTLY as the round-3 PASSING artifact (plain __has_builtin).
#ifndef __has_builtin
#define __has_builtin(x) 0
#endif
#if __has_builtin(__builtin_amdgcn_mfma_f32_16x16x32_bf16)
#define HAVE_MFMA 1
#else
#define HAVE_MFMA 0
#endif

using bf16x8 = __attribute__((ext_vector_type(8))) short;  // guide-verified frag type
using f32x4  = __attribute__((ext_vector_type(4))) float;
typedef unsigned short u16;
typedef unsigned int u32;

#define BN 2048
#define DD 128
#define EE 64
#define HH 256

__device__ __forceinline__ float bf2f(u16 u) {
  union { u32 i; float f; } c; c.i = ((u32)u) << 16; return c.f;
}
__device__ __forceinline__ u16 f2bf(float f) {  // RNE
  union { float f; u32 i; } c; c.f = f;
  u32 x = c.i; u32 r = x + 0x7FFFu + ((x >> 16) & 1u);
  return (u16)(r >> 16);
}
__device__ __forceinline__ float ldT(const float* p, int i) { return p[i]; }
__device__ __forceinline__ float ldT(const u16* p, int i) { return bf2f(p[i]); }

// swizzled LDS addressing (16B chunks xor'ed by row&7)
__device__ __forceinline__ int swz(int row, int e) {
  int c = e >> 3, r = e & 7;
  return row * 64 + (((c ^ (row & 7)) << 3) | r);
}

// stage 8 source elems -> 8 bf16 shorts at 16B-aligned LDS dst
__device__ __forceinline__ void stage8(const u16* s, u16* d) {
  *(float4*)d = *(const float4*)s;
}
__device__ __forceinline__ void stage8(const float* s, u16* d) {
  float4 a = *(const float4*)s, b = *(const float4*)(s + 4);
  d[0]=f2bf(a.x); d[1]=f2bf(a.y); d[2]=f2bf(a.z); d[3]=f2bf(a.w);
  d[4]=f2bf(b.x); d[5]=f2bf(b.y); d[6]=f2bf(b.z); d[7]=f2bf(b.w);
}

// ---------------------------------------------------------------------------
// detect dtype of inputs + write canary 1.0 to out.  (round-3 verbatim)
// ---------------------------------------------------------------------------
__global__ __launch_bounds__(256) void k_detect(const u16* __restrict__ nodes_u16,
                                                int* __restrict__ flag,
                                                void* __restrict__ out, int out_n) {
  __shared__ int cnt;
  __shared__ int fl;
  const int t = threadIdx.x;
  if (t == 0) cnt = 0;
  __syncthreads();
  u16 v = nodes_u16[t * 1024];
  int e = (v >> 7) & 0xFF;
  atomicAdd(&cnt, (e >= 0x70 && e <= 0x8F) ? 1 : 0);
  __syncthreads();
  if (t == 0) { fl = (cnt >= 128) ? 1 : 0; *flag = fl; }
  __syncthreads();
  if (fl) {
    u16* o = (u16*)out;
    for (int i = t; i < out_n; i += 256) o[i] = 0x3F80;
  } else {
    float* o = (float*)out;
    for (int i = t; i < out_n; i += 256) o[i] = 1.0f;
  }
}

// ---------------------------------------------------------------------------
// canonicalize all 14 weight tensors to fp32 in ws (round-3 verbatim)
// ---------------------------------------------------------------------------
struct WPtrs { const void* p[14]; };

template <typename T>
__global__ __launch_bounds__(256) void k_cvtw(WPtrs wp, const int* __restrict__ flag,
                                              float* __restrict__ canon, int want) {
  if (*flag != want) return;
  const int lens[14] = {147456, 768, 196608, 768, 294912, 768, 98304, 384,
                        384, 384, 32768, 256, 32768, 128};
  const int gid = blockIdx.x * 256 + threadIdx.x;
  const int gsz = gridDim.x * 256;
  int off = 0;
  for (int s = 0; s < 14; s++) {
    const T* src = (const T*)wp.p[s];
    float* dst = canon + off;
    for (int i = gid; i < lens[s]; i += gsz) dst[i] = ldT(src, i);
    off += lens[s];
  }
}

template <typename T>
__global__ __launch_bounds__(256) void k_cvtn(const T* __restrict__ nodes,
                                              const int* __restrict__ flag,
                                              float* __restrict__ xbuf, int want) {
  if (*flag != want) return;
  const int gid = blockIdx.x * 256 + threadIdx.x;
  const int gsz = gridDim.x * 256;
  for (int i = gid; i < BN * DD; i += gsz) xbuf[i] = ldT(nodes, i);
}

// ---------------------------------------------------------------------------
// NEW: fuse the aggregate GEMM into the update MLP (exact linear algebra):
//   agg @ uw1b = hsum @ (w2 @ uw1b) + 128*(b2 @ uw1b)
// W2U = w2@uw1b overwrites canon's (dead) msg_w2 slot; ub1' = ub1+128*b2@uw1b
// overwrites the msg_b2 slot. Reads ORIGINAL (typed) globals -> no in-place
// hazard; runs after k_cvtw so the overwrite sticks.
// grid = 3*257: blocks 0..255 of a layer = W2U rows; block 256 = bias row.
// ---------------------------------------------------------------------------
template <typename T>
__global__ __launch_bounds__(256) void k_fuse(
    const T* __restrict__ msg_w2,   // [3][256][256]
    const T* __restrict__ msg_b2,   // [3][256]
    const T* __restrict__ upd_w1,   // [3][384][256]
    const T* __restrict__ upd_b1,   // [3][256]
    const int* __restrict__ flag, int want,
    float* __restrict__ w2uC,       // canon+MW2: [3][256][256]
    float* __restrict__ b2uC) {     // canon+MB2: [3][256]
  if (*flag != want) return;
  const int l = blockIdx.x / 257;
  const int k = blockIdx.x % 257;
  const int c = threadIdx.x;
  const T* uw1b = upd_w1 + (size_t)l * 384 * HH + (size_t)DD * HH;  // [256][256]
  __shared__ float row[HH];
  if (k < 256) {
    row[c] = ldT(msg_w2 + (size_t)l * 65536 + (size_t)k * HH, c);
    __syncthreads();
    float acc = 0.f;
    #pragma unroll 8
    for (int m = 0; m < HH; m++) acc = fmaf(row[m], ldT(uw1b, m * HH + c), acc);
    w2uC[(size_t)l * 65536 + (size_t)k * HH + c] = acc;
  } else {
    row[c] = ldT(msg_b2 + (size_t)l * HH, c);
    __syncthreads();
    float acc = 0.f;
    #pragma unroll 8
    for (int m = 0; m < HH; m++) acc = fmaf(row[m], ldT(uw1b, m * HH + c), acc);
    b2uC[l * HH + c] = ldT(upd_b1 + (size_t)l * HH, c) + 128.f * acc;
  }
}

// ---------------------------------------------------------------------------
// per (b,i): hsum[bi][h] = sum_j relu( npart[h] + edges[bi][j][:] @ W1e[:,h] )
// (round-3 verbatim — PASSING kernel, untouched)
// ---------------------------------------------------------------------------
template <typename T>
__global__ __launch_bounds__(256) void k_edge(
    const T* __restrict__ edges, const int* __restrict__ flag, int want,
    const float* __restrict__ xbuf,
    const float* __restrict__ w1C,   // layer base of msg_w1 canon [192][256]
    const float* __restrict__ b1C,   // [256]
    float* __restrict__ hsum) {
  if (*flag != want) return;
  __shared__ __align__(16) u16 eL[128 * 64];
  __shared__ __align__(16) u16 wL[256 * 64];
  __shared__ float npL[256];

  const int bi = blockIdx.x;
  const int t = threadIdx.x;

  const T* eg = edges + (size_t)bi * (128 * 64);
  #pragma unroll
  for (int q = 0; q < 4; q++) {
    int idx = q * 256 + t;
    int j = idx >> 3, c = idx & 7;
    stage8(eg + j * 64 + c * 8, &eL[j * 64 + ((c ^ (j & 7)) * 8)]);
  }
  {
    const float* we = w1C + 128 * 256;  // we[e*256 + h]
    #pragma unroll
    for (int c = 0; c < 8; c++) {
      u16 tmp[8];
      #pragma unroll
      for (int j = 0; j < 8; j++) tmp[j] = f2bf(we[(c * 8 + j) * 256 + t]);
      *(float4*)(&wL[t * 64 + ((c ^ (t & 7)) * 8)]) = *(const float4*)tmp;
    }
  }
  {
    const float* xr = xbuf + (size_t)bi * DD;
    float acc = b1C[t];
    #pragma unroll 8
    for (int k = 0; k < DD; k++) acc = fmaf(xr[k], w1C[k * 256 + t], acc);
    npL[t] = acc;
  }
  __syncthreads();

#if HAVE_MFMA
  const int lane = t & 63;
  const int w = t >> 6;
  const int lr = lane & 15;
  const int quad = lane >> 4;

  bf16x8 afr[8][2];
  #pragma unroll
  for (int jt = 0; jt < 8; jt++) {
    int m = jt * 16 + lr;
    #pragma unroll
    for (int kc = 0; kc < 2; kc++) {
      int c8 = kc * 4 + quad;
      afr[jt][kc] = *(const bf16x8*)(&eL[m * 64 + ((c8 ^ (m & 7)) * 8)]);
    }
  }
  float* hrow = hsum + (size_t)bi * HH;
  #pragma unroll
  for (int ht = 0; ht < 4; ht++) {
    const int n = w * 64 + ht * 16 + lr;
    bf16x8 bf0 = *(const bf16x8*)(&wL[n * 64 + (((0 + quad) ^ (n & 7)) * 8)]);
    bf16x8 bf1 = *(const bf16x8*)(&wL[n * 64 + (((4 + quad) ^ (n & 7)) * 8)]);
    const float npv = npL[n];
    float colsum = 0.f;
    #pragma unroll
    for (int jt = 0; jt < 8; jt++) {
      f32x4 acc = {0.f, 0.f, 0.f, 0.f};
      acc = __builtin_amdgcn_mfma_f32_16x16x32_bf16(afr[jt][0], bf0, acc, 0, 0, 0);
      acc = __builtin_amdgcn_mfma_f32_16x16x32_bf16(afr[jt][1], bf1, acc, 0, 0, 0);
      #pragma unroll
      for (int r = 0; r < 4; r++) colsum += fmaxf(acc[r] + npv, 0.f);
    }
    colsum += __shfl_xor(colsum, 16);
    colsum += __shfl_xor(colsum, 32);
    if (quad == 0) hrow[n] = colsum;
  }
#else
  float hs = 0.f;
  for (int j = 0; j < 128; j++) {
    float p = npL[t];
    for (int e = 0; e < 64; e++)
      p = fmaf(bf2f(eL[swz(j, e)]), bf2f(wL[swz(t, e)]), p);
    hs += fmaxf(p, 0.f);
  }
  hsum[(size_t)bi * HH + t] = hs;
#endif
}

// ---------------------------------------------------------------------------
// NEW: u1 = relu( x@uw1a + hsum@W2U + ub1' ).  512 blocks x 4 rows x 256 cols.
// In-place: u1 overwrites hsum (rows exclusively owned; staged to LDS first).
// ---------------------------------------------------------------------------
__global__ __launch_bounds__(256) void k_mlp1(
    const float* __restrict__ xbuf,  // [2048][128]
    float* __restrict__ hs_u1,       // [2048][256] hsum in / u1 out
    const float* __restrict__ uw1a,  // [128][256] (canon UW1 rows 0..127)
    const float* __restrict__ w2u,   // [256][256] (canon MW2 slot, fused)
    const float* __restrict__ bias) {// [256]      (canon MB2 slot, fused)
  __shared__ float xs[4 * DD];
  __shared__ float hl[4 * HH];
  const int t = threadIdx.x;
  const int r0 = blockIdx.x * 4;
  #pragma unroll
  for (int q = 0; q < 2; q++)
    xs[q * 256 + t] = xbuf[(size_t)r0 * DD + q * 256 + t];
  #pragma unroll
  for (int q = 0; q < 4; q++)
    hl[q * 256 + t] = hs_u1[(size_t)r0 * HH + q * 256 + t];
  __syncthreads();
  float a0 = 0.f, a1 = 0.f, a2 = 0.f, a3 = 0.f;
  #pragma unroll 8
  for (int k = 0; k < DD; k++) {
    float wv = uw1a[k * HH + t];
    a0 = fmaf(xs[0 * DD + k], wv, a0);
    a1 = fmaf(xs[1 * DD + k], wv, a1);
    a2 = fmaf(xs[2 * DD + k], wv, a2);
    a3 = fmaf(xs[3 * DD + k], wv, a3);
  }
  #pragma unroll 8
  for (int k = 0; k < HH; k++) {
    float wv = w2u[k * HH + t];
    a0 = fmaf(hl[0 * HH + k], wv, a0);
    a1 = fmaf(hl[1 * HH + k], wv, a1);
    a2 = fmaf(hl[2 * HH + k], wv, a2);
    a3 = fmaf(hl[3 * HH + k], wv, a3);
  }
  float bv = bias[t];
  hs_u1[(size_t)(r0 + 0) * HH + t] = fmaxf(a0 + bv, 0.f);
  hs_u1[(size_t)(r0 + 1) * HH + t] = fmaxf(a1 + bv, 0.f);
  hs_u1[(size_t)(r0 + 2) * HH + t] = fmaxf(a2 + bv, 0.f);
  hs_u1[(size_t)(r0 + 3) * HH + t] = fmaxf(a3 + bv, 0.f);
}

// ---------------------------------------------------------------------------
// NEW: y = x + u1@uw2 + ub2; layernorm -> xbuf in place. 1024 blocks x 2 rows.
// thread = (r = t>>7, c = t&127); wave shfl reduce + 2-wave LDS combine.
// ---------------------------------------------------------------------------
__global__ __launch_bounds__(256) void k_mlp2ln(
    const float* __restrict__ u1, float* __restrict__ xbuf,
    const float* __restrict__ uw2, const float* __restrict__ ub2,
    const float* __restrict__ lng, const float* __restrict__ lnb) {
  __shared__ float ul[2 * HH];
  __shared__ float red[8];
  const int t = threadIdx.x;
  const int r0 = blockIdx.x * 2;
  const int r = t >> 7, c = t & 127;
  ul[t] = u1[(size_t)r0 * HH + t];
  ul[256 + t] = u1[(size_t)r0 * HH + 256 + t];
  __syncthreads();
  float acc = 0.f;
  const float* ur = &ul[r * HH];
  #pragma unroll 8
  for (int k = 0; k < HH; k++) acc = fmaf(ur[k], uw2[k * DD + c], acc);
  float y = xbuf[(size_t)(r0 + r) * DD + c] + acc + ub2[c];
  float s = y, ss = y * y;
  #pragma unroll
  for (int m = 1; m < 64; m <<= 1) {
    s += __shfl_xor(s, m);
    ss += __shfl_xor(ss, m);
  }
  const int w = t >> 6;
  if ((t & 63) == 0) { red[w * 2] = s; red[w * 2 + 1] = ss; }
  __syncthreads();
  const int wb = (r == 0) ? 0 : 4;
  float S = red[wb] + red[wb + 2];
  float SS = red[wb + 1] + red[wb + 3];
  float mean = S * (1.f / 128.f);
  float var = SS * (1.f / 128.f) - mean * mean;
  float rs = rsqrtf(var + 1e-5f);
  xbuf[(size_t)(r0 + r) * DD + c] = (y - mean) * rs * lng[c] + lnb[c];
}

// ---------------------------------------------------------------------------
// NEW: u1o = relu(x@ow1 + ob1). 512 blocks x 4 rows (u1o = hsum region, dead).
// ---------------------------------------------------------------------------
__global__ __launch_bounds__(256) void k_out1(
    const float* __restrict__ xbuf, float* __restrict__ u1o,
    const float* __restrict__ ow1, const float* __restrict__ ob1) {
  __shared__ float xs[4 * DD];
  const int t = threadIdx.x;
  const int r0 = blockIdx.x * 4;
  #pragma unroll
  for (int q = 0; q < 2; q++)
    xs[q * 256 + t] = xbuf[(size_t)r0 * DD + q * 256 + t];
  __syncthreads();
  float a0 = 0.f, a1 = 0.f, a2 = 0.f, a3 = 0.f;
  #pragma unroll 8
  for (int k = 0; k < DD; k++) {
    float wv = ow1[k * HH + t];
    a0 = fmaf(xs[0 * DD + k], wv, a0);
    a1 = fmaf(xs[1 * DD + k], wv, a1);
    a2 = fmaf(xs[2 * DD + k], wv, a2);
    a3 = fmaf(xs[3 * DD + k], wv, a3);
  }
  float bv = ob1[t];
  u1o[(size_t)(r0 + 0) * HH + t] = fmaxf(a0 + bv, 0.f);
  u1o[(size_t)(r0 + 1) * HH + t] = fmaxf(a1 + bv, 0.f);
  u1o[(size_t)(r0 + 2) * HH + t] = fmaxf(a2 + bv, 0.f);
  u1o[(size_t)(r0 + 3) * HH + t] = fmaxf(a3 + bv, 0.f);
}

// ---------------------------------------------------------------------------
// NEW: out = u1o@ow2 + ob2, stored per flag dtype. 1024 blocks x 2 rows.
// ---------------------------------------------------------------------------
__global__ __launch_bounds__(256) void k_out2(
    const float* __restrict__ u1o, const float* __restrict__ ow2,
    const float* __restrict__ ob2, const int* __restrict__ flag,
    void* __restrict__ out) {
  __shared__ float ul[2 * HH];
  const int t = threadIdx.x;
  const int r0 = blockIdx.x * 2;
  const int r = t >> 7, c = t & 127;
  ul[t] = u1o[(size_t)r0 * HH + t];
  ul[256 + t] = u1o[(size_t)r0 * HH + 256 + t];
  __syncthreads();
  float acc = 0.f;
  const float* ur = &ul[r * HH];
  #pragma unroll 8
  for (int k = 0; k < HH; k++) acc = fmaf(ur[k], ow2[k * DD + c], acc);
  float v = acc + ob2[c];
  size_t o = (size_t)(r0 + r) * DD + c;
  if (*flag) ((u16*)out)[o] = f2bf(v);
  else ((float*)out)[o] = v;
}

extern "C" void kernel_launch(void* const* d_in, const int* in_sizes, int n_in,
                              void* d_out, int out_size, void* d_ws,
                              size_t ws_size, hipStream_t stream) {
  const int wb = (n_in >= 17 && in_sizes[2] == 2048) ? 3 : 2;

  char* ws = (char*)d_ws;
  int* flag    = (int*)ws;                                 // @0
  float* xbuf  = (float*)(ws + 4096);                      // 1 MB
  float* hsum  = (float*)(ws + 4096 + 1048576);            // 2 MB (also u1/u1o)
  float* canon = (float*)(ws + 4096 + 1048576 + 2097152);  // 3.23 MB

  WPtrs wp;
  for (int i = 0; i < 14; i++) wp.p[i] = d_in[wb + i];

  // canon float offsets (round-3 verbatim)
  const int MW1 = 0, MB1 = 147456, MW2 = 148224, MB2 = 344832, UW1 = 345600,
            UB1 = 640512, UW2 = 641280, UB2 = 739584, LNG = 739968,
            LNB = 740352, OW1 = 740736, OB1 = 773504, OW2 = 773760,
            OB2 = 806528;
  (void)UB1;

  k_detect<<<1, 256, 0, stream>>>((const u16*)d_in[0], flag, d_out, out_size);
  k_cvtw<float><<<512, 256, 0, stream>>>(wp, flag, canon, 0);
  k_cvtw<u16><<<512, 256, 0, stream>>>(wp, flag, canon, 1);
  k_cvtn<float><<<256, 256, 0, stream>>>((const float*)d_in[0], flag, xbuf, 0);
  k_cvtn<u16><<<256, 256, 0, stream>>>((const u16*)d_in[0], flag, xbuf, 1);
  // fuse AFTER cvtw (it overwrites canon MW2/MB2 slots, reading typed globals)
  k_fuse<float><<<771, 256, 0, stream>>>(
      (const float*)d_in[wb + 2], (const float*)d_in[wb + 3],
      (const float*)d_in[wb + 4], (const float*)d_in[wb + 5], flag, 0,
      canon + MW2, canon + MB2);
  k_fuse<u16><<<771, 256, 0, stream>>>(
      (const u16*)d_in[wb + 2], (const u16*)d_in[wb + 3],
      (const u16*)d_in[wb + 4], (const u16*)d_in[wb + 5], flag, 1,
      canon + MW2, canon + MB2);

  for (int l = 0; l < 3; l++) {
    const float* w1C = canon + MW1 + l * 49152;
    const float* b1C = canon + MB1 + l * 256;
    k_edge<float><<<BN, 256, 0, stream>>>((const float*)d_in[1], flag, 0, xbuf,
                                          w1C, b1C, hsum);
    k_edge<u16><<<BN, 256, 0, stream>>>((const u16*)d_in[1], flag, 1, xbuf,
                                        w1C, b1C, hsum);
    k_mlp1<<<512, 256, 0, stream>>>(xbuf, hsum, canon + UW1 + l * 98304,
                                    canon + MW2 + l * 65536,
                                    canon + MB2 + l * 256);
    k_mlp2ln<<<1024, 256, 0, stream>>>(hsum, xbuf, canon + UW2 + l * 32768,
                                       canon + UB2 + l * 128,
                                       canon + LNG + l * 128,
                                       canon + LNB + l * 128);
  }
  k_out1<<<512, 256, 0, stream>>>(xbuf, hsum, canon + OW1, canon + OB1);
  k_out2<<<1024, 256, 0, stream>>>(hsum, canon + OW2, canon + OB2, flag,
                                   d_out);
}

// Round 8
// 378.802 us; speedup vs baseline: 1.2106x; 1.0224x over previous
//
#include <hip/hip_runtime.h>

// No hip_bf16.h: hand-rolled bf16<->f32 to minimize compile-failure surface.
// Preamble kept EXACTLY as the round-3/round-6 PASSING artifacts.
#ifndef __has_builtin
#define __has_builtin(x) 0
#endif
#if __has_builtin(__builtin_amdgcn_mfma_f32_16x16x32_bf16)
#define HAVE_MFMA 1
#else
#define HAVE_MFMA 0
#endif

using bf16x8 = __attribute__((ext_vector_type(8))) short;  // guide-verified frag type
using f32x4  = __attribute__((ext_vector_type(4))) float;
typedef unsigned short u16;
typedef unsigned int u32;

#define BN 2048
#define DD 128
#define EE 64
#define HH 256

__device__ __forceinline__ float bf2f(u16 u) {
  union { u32 i; float f; } c; c.i = ((u32)u) << 16; return c.f;
}
__device__ __forceinline__ u16 f2bf(float f) {  // RNE
  union { float f; u32 i; } c; c.f = f;
  u32 x = c.i; u32 r = x + 0x7FFFu + ((x >> 16) & 1u);
  return (u16)(r >> 16);
}
__device__ __forceinline__ float ldT(const float* p, int i) { return p[i]; }
__device__ __forceinline__ float ldT(const u16* p, int i) { return bf2f(p[i]); }

// swizzled LDS addressing (16B chunks xor'ed by row&7)
__device__ __forceinline__ int swz(int row, int e) {
  int c = e >> 3, r = e & 7;
  return row * 64 + (((c ^ (row & 7)) << 3) | r);
}

// stage 8 source elems -> 8 bf16 shorts at 16B-aligned LDS dst
__device__ __forceinline__ void stage8(const u16* s, u16* d) {
  *(float4*)d = *(const float4*)s;
}
__device__ __forceinline__ void stage8(const float* s, u16* d) {
  float4 a = *(const float4*)s, b = *(const float4*)(s + 4);
  d[0]=f2bf(a.x); d[1]=f2bf(a.y); d[2]=f2bf(a.z); d[3]=f2bf(a.w);
  d[4]=f2bf(b.x); d[5]=f2bf(b.y); d[6]=f2bf(b.z); d[7]=f2bf(b.w);
}

// ---------------------------------------------------------------------------
// detect dtype of inputs + write canary 1.0 to out.  (round-6 verbatim)
// ---------------------------------------------------------------------------
__global__ __launch_bounds__(256) void k_detect(const u16* __restrict__ nodes_u16,
                                                int* __restrict__ flag,
                                                void* __restrict__ out, int out_n) {
  __shared__ int cnt;
  __shared__ int fl;
  const int t = threadIdx.x;
  if (t == 0) cnt = 0;
  __syncthreads();
  u16 v = nodes_u16[t * 1024];
  int e = (v >> 7) & 0xFF;
  atomicAdd(&cnt, (e >= 0x70 && e <= 0x8F) ? 1 : 0);
  __syncthreads();
  if (t == 0) { fl = (cnt >= 128) ? 1 : 0; *flag = fl; }
  __syncthreads();
  if (fl) {
    u16* o = (u16*)out;
    for (int i = t; i < out_n; i += 256) o[i] = 0x3F80;
  } else {
    float* o = (float*)out;
    for (int i = t; i < out_n; i += 256) o[i] = 1.0f;
  }
}

// ---------------------------------------------------------------------------
// canonicalize all 14 weight tensors to fp32 in ws (round-6 verbatim)
// ---------------------------------------------------------------------------
struct WPtrs { const void* p[14]; };

template <typename T>
__global__ __launch_bounds__(256) void k_cvtw(WPtrs wp, const int* __restrict__ flag,
                                              float* __restrict__ canon, int want) {
  if (*flag != want) return;
  const int lens[14] = {147456, 768, 196608, 768, 294912, 768, 98304, 384,
                        384, 384, 32768, 256, 32768, 128};
  const int gid = blockIdx.x * 256 + threadIdx.x;
  const int gsz = gridDim.x * 256;
  int off = 0;
  for (int s = 0; s < 14; s++) {
    const T* src = (const T*)wp.p[s];
    float* dst = canon + off;
    for (int i = gid; i < lens[s]; i += gsz) dst[i] = ldT(src, i);
    off += lens[s];
  }
}

template <typename T>
__global__ __launch_bounds__(256) void k_cvtn(const T* __restrict__ nodes,
                                              const int* __restrict__ flag,
                                              float* __restrict__ xbuf, int want) {
  if (*flag != want) return;
  const int gid = blockIdx.x * 256 + threadIdx.x;
  const int gsz = gridDim.x * 256;
  for (int i = gid; i < BN * DD; i += gsz) xbuf[i] = ldT(nodes, i);
}

// ---------------------------------------------------------------------------
// NEW (only change this round): pre-transpose msg_w1[l][128:192][:] (64x256)
// to bf16 wt[l][256][64] stored INSIDE canon's MW1 rows 128..191 slot — that
// fp32 region is dead once wt exists (k_edge's wL came from it). Runs AFTER
// k_cvtw (overwrite sticks); reads ORIGINAL typed globals (no hazard).
// grid 3 (one block per layer).
// ---------------------------------------------------------------------------
template <typename T>
__global__ __launch_bounds__(256) void k_prep(
    const T* __restrict__ msg_w1, const int* __restrict__ flag, int want,
    float* __restrict__ canonMW1) {
  if (*flag != want) return;
  const int l = blockIdx.x, t = threadIdx.x;
  const T* src = msg_w1 + (size_t)l * 192 * HH + (size_t)DD * HH;  // [64][256]
  u16* dst = (u16*)(canonMW1 + (size_t)l * 49152 + 128 * 256);     // [256][64] bf16
  #pragma unroll 8
  for (int k = 0; k < EE; k++) dst[t * EE + k] = f2bf(ldT(src, k * HH + t));
}

// ---------------------------------------------------------------------------
// per (b,i): hsum[bi][h] = sum_j relu( npart[h] + edges[bi][j][:] @ W1e[:,h] )
// (round-6 structure; CHANGED: wL staged via float4 copies from pre-transposed
// bf16 wt; npart x read from LDS stage. MFMA fragment math byte-identical.)
// ---------------------------------------------------------------------------
template <typename T>
__global__ __launch_bounds__(256) void k_edge(
    const T* __restrict__ edges, const int* __restrict__ flag, int want,
    const float* __restrict__ xbuf,
    const float* __restrict__ w1C,   // layer base of msg_w1 canon [192][256]
    const float* __restrict__ b1C,   // [256]
    float* __restrict__ hsum) {
  if (*flag != want) return;
  __shared__ __align__(16) u16 eL[128 * 64];
  __shared__ __align__(16) u16 wL[256 * 64];
  __shared__ float npL[256];
  __shared__ float xs[DD];

  const int bi = blockIdx.x;
  const int t = threadIdx.x;

  if (t < DD) xs[t] = xbuf[(size_t)bi * DD + t];

  const T* eg = edges + (size_t)bi * (128 * 64);
  #pragma unroll
  for (int q = 0; q < 4; q++) {
    int idx = q * 256 + t;
    int j = idx >> 3, c = idx & 7;
    stage8(eg + j * 64 + c * 8, &eL[j * 64 + ((c ^ (j & 7)) * 8)]);
  }
  {
    const u16* wtl = (const u16*)(w1C + 128 * 256);  // pre-transposed [256][64]
    #pragma unroll
    for (int q = 0; q < 8; q++) {
      int idx = q * 256 + t;
      int hh = idx >> 3, c = idx & 7;
      *(float4*)(&wL[hh * 64 + ((c ^ (hh & 7)) * 8)]) =
          *(const float4*)(wtl + hh * 64 + c * 8);
    }
  }
  __syncthreads();
  {
    float acc = b1C[t];
    #pragma unroll 8
    for (int k = 0; k < DD; k++) acc = fmaf(xs[k], w1C[k * 256 + t], acc);
    npL[t] = acc;
  }
  __syncthreads();

#if HAVE_MFMA
  const int lane = t & 63;
  const int w = t >> 6;
  const int lr = lane & 15;
  const int quad = lane >> 4;

  bf16x8 afr[8][2];
  #pragma unroll
  for (int jt = 0; jt < 8; jt++) {
    int m = jt * 16 + lr;
    #pragma unroll
    for (int kc = 0; kc < 2; kc++) {
      int c8 = kc * 4 + quad;
      afr[jt][kc] = *(const bf16x8*)(&eL[m * 64 + ((c8 ^ (m & 7)) * 8)]);
    }
  }
  float* hrow = hsum + (size_t)bi * HH;
  #pragma unroll
  for (int ht = 0; ht < 4; ht++) {
    const int n = w * 64 + ht * 16 + lr;
    bf16x8 bf0 = *(const bf16x8*)(&wL[n * 64 + (((0 + quad) ^ (n & 7)) * 8)]);
    bf16x8 bf1 = *(const bf16x8*)(&wL[n * 64 + (((4 + quad) ^ (n & 7)) * 8)]);
    const float npv = npL[n];
    float colsum = 0.f;
    #pragma unroll
    for (int jt = 0; jt < 8; jt++) {
      f32x4 acc = {0.f, 0.f, 0.f, 0.f};
      acc = __builtin_amdgcn_mfma_f32_16x16x32_bf16(afr[jt][0], bf0, acc, 0, 0, 0);
      acc = __builtin_amdgcn_mfma_f32_16x16x32_bf16(afr[jt][1], bf1, acc, 0, 0, 0);
      #pragma unroll
      for (int r = 0; r < 4; r++) colsum += fmaxf(acc[r] + npv, 0.f);
    }
    colsum += __shfl_xor(colsum, 16);
    colsum += __shfl_xor(colsum, 32);
    if (quad == 0) hrow[n] = colsum;
  }
#else
  float hs = 0.f;
  for (int j = 0; j < 128; j++) {
    float p = npL[t];
    for (int e = 0; e < 64; e++)
      p = fmaf(bf2f(eL[swz(j, e)]), bf2f(wL[swz(t, e)]), p);
    hs += fmaxf(p, 0.f);
  }
  hsum[(size_t)bi * HH + t] = hs;
#endif
}

// ---------------------------------------------------------------------------
// fuse the aggregate GEMM into the update MLP (round-6 verbatim)
// ---------------------------------------------------------------------------
template <typename T>
__global__ __launch_bounds__(256) void k_fuse(
    const T* __restrict__ msg_w2,   // [3][256][256]
    const T* __restrict__ msg_b2,   // [3][256]
    const T* __restrict__ upd_w1,   // [3][384][256]
    const T* __restrict__ upd_b1,   // [3][256]
    const int* __restrict__ flag, int want,
    float* __restrict__ w2uC,       // canon+MW2: [3][256][256]
    float* __restrict__ b2uC) {     // canon+MB2: [3][256]
  if (*flag != want) return;
  const int l = blockIdx.x / 257;
  const int k = blockIdx.x % 257;
  const int c = threadIdx.x;
  const T* uw1b = upd_w1 + (size_t)l * 384 * HH + (size_t)DD * HH;  // [256][256]
  __shared__ float row[HH];
  if (k < 256) {
    row[c] = ldT(msg_w2 + (size_t)l * 65536 + (size_t)k * HH, c);
    __syncthreads();
    float acc = 0.f;
    #pragma unroll 8
    for (int m = 0; m < HH; m++) acc = fmaf(row[m], ldT(uw1b, m * HH + c), acc);
    w2uC[(size_t)l * 65536 + (size_t)k * HH + c] = acc;
  } else {
    row[c] = ldT(msg_b2 + (size_t)l * HH, c);
    __syncthreads();
    float acc = 0.f;
    #pragma unroll 8
    for (int m = 0; m < HH; m++) acc = fmaf(row[m], ldT(uw1b, m * HH + c), acc);
    b2uC[l * HH + c] = ldT(upd_b1 + (size_t)l * HH, c) + 128.f * acc;
  }
}

// ---------------------------------------------------------------------------
// u1 = relu( x@uw1a + hsum@W2U + ub1' ).  (round-6 verbatim)
// ---------------------------------------------------------------------------
__global__ __launch_bounds__(256) void k_mlp1(
    const float* __restrict__ xbuf,  // [2048][128]
    float* __restrict__ hs_u1,       // [2048][256] hsum in / u1 out
    const float* __restrict__ uw1a,  // [128][256] (canon UW1 rows 0..127)
    const float* __restrict__ w2u,   // [256][256] (canon MW2 slot, fused)
    const float* __restrict__ bias) {// [256]      (canon MB2 slot, fused)
  __shared__ float xs[4 * DD];
  __shared__ float hl[4 * HH];
  const int t = threadIdx.x;
  const int r0 = blockIdx.x * 4;
  #pragma unroll
  for (int q = 0; q < 2; q++)
    xs[q * 256 + t] = xbuf[(size_t)r0 * DD + q * 256 + t];
  #pragma unroll
  for (int q = 0; q < 4; q++)
    hl[q * 256 + t] = hs_u1[(size_t)r0 * HH + q * 256 + t];
  __syncthreads();
  float a0 = 0.f, a1 = 0.f, a2 = 0.f, a3 = 0.f;
  #pragma unroll 8
  for (int k = 0; k < DD; k++) {
    float wv = uw1a[k * HH + t];
    a0 = fmaf(xs[0 * DD + k], wv, a0);
    a1 = fmaf(xs[1 * DD + k], wv, a1);
    a2 = fmaf(xs[2 * DD + k], wv, a2);
    a3 = fmaf(xs[3 * DD + k], wv, a3);
  }
  #pragma unroll 8
  for (int k = 0; k < HH; k++) {
    float wv = w2u[k * HH + t];
    a0 = fmaf(hl[0 * HH + k], wv, a0);
    a1 = fmaf(hl[1 * HH + k], wv, a1);
    a2 = fmaf(hl[2 * HH + k], wv, a2);
    a3 = fmaf(hl[3 * HH + k], wv, a3);
  }
  float bv = bias[t];
  hs_u1[(size_t)(r0 + 0) * HH + t] = fmaxf(a0 + bv, 0.f);
  hs_u1[(size_t)(r0 + 1) * HH + t] = fmaxf(a1 + bv, 0.f);
  hs_u1[(size_t)(r0 + 2) * HH + t] = fmaxf(a2 + bv, 0.f);
  hs_u1[(size_t)(r0 + 3) * HH + t] = fmaxf(a3 + bv, 0.f);
}

// ---------------------------------------------------------------------------
// y = x + u1@uw2 + ub2; layernorm -> xbuf in place. (round-6 verbatim)
// ---------------------------------------------------------------------------
__global__ __launch_bounds__(256) void k_mlp2ln(
    const float* __restrict__ u1, float* __restrict__ xbuf,
    const float* __restrict__ uw2, const float* __restrict__ ub2,
    const float* __restrict__ lng, const float* __restrict__ lnb) {
  __shared__ float ul[2 * HH];
  __shared__ float red[8];
  const int t = threadIdx.x;
  const int r0 = blockIdx.x * 2;
  const int r = t >> 7, c = t & 127;
  ul[t] = u1[(size_t)r0 * HH + t];
  ul[256 + t] = u1[(size_t)r0 * HH + 256 + t];
  __syncthreads();
  float acc = 0.f;
  const float* ur = &ul[r * HH];
  #pragma unroll 8
  for (int k = 0; k < HH; k++) acc = fmaf(ur[k], uw2[k * DD + c], acc);
  float y = xbuf[(size_t)(r0 + r) * DD + c] + acc + ub2[c];
  float s = y, ss = y * y;
  #pragma unroll
  for (int m = 1; m < 64; m <<= 1) {
    s += __shfl_xor(s, m);
    ss += __shfl_xor(ss, m);
  }
  const int w = t >> 6;
  if ((t & 63) == 0) { red[w * 2] = s; red[w * 2 + 1] = ss; }
  __syncthreads();
  const int wb = (r == 0) ? 0 : 4;
  float S = red[wb] + red[wb + 2];
  float SS = red[wb + 1] + red[wb + 3];
  float mean = S * (1.f / 128.f);
  float var = SS * (1.f / 128.f) - mean * mean;
  float rs = rsqrtf(var + 1e-5f);
  xbuf[(size_t)(r0 + r) * DD + c] = (y - mean) * rs * lng[c] + lnb[c];
}

// ---------------------------------------------------------------------------
// u1o = relu(x@ow1 + ob1). (round-6 verbatim)
// ---------------------------------------------------------------------------
__global__ __launch_bounds__(256) void k_out1(
    const float* __restrict__ xbuf, float* __restrict__ u1o,
    const float* __restrict__ ow1, const float* __restrict__ ob1) {
  __shared__ float xs[4 * DD];
  const int t = threadIdx.x;
  const int r0 = blockIdx.x * 4;
  #pragma unroll
  for (int q = 0; q < 2; q++)
    xs[q * 256 + t] = xbuf[(size_t)r0 * DD + q * 256 + t];
  __syncthreads();
  float a0 = 0.f, a1 = 0.f, a2 = 0.f, a3 = 0.f;
  #pragma unroll 8
  for (int k = 0; k < DD; k++) {
    float wv = ow1[k * HH + t];
    a0 = fmaf(xs[0 * DD + k], wv, a0);
    a1 = fmaf(xs[1 * DD + k], wv, a1);
    a2 = fmaf(xs[2 * DD + k], wv, a2);
    a3 = fmaf(xs[3 * DD + k], wv, a3);
  }
  float bv = ob1[t];
  u1o[(size_t)(r0 + 0) * HH + t] = fmaxf(a0 + bv, 0.f);
  u1o[(size_t)(r0 + 1) * HH + t] = fmaxf(a1 + bv, 0.f);
  u1o[(size_t)(r0 + 2) * HH + t] = fmaxf(a2 + bv, 0.f);
  u1o[(size_t)(r0 + 3) * HH + t] = fmaxf(a3 + bv, 0.f);
}

// ---------------------------------------------------------------------------
// out = u1o@ow2 + ob2, stored per flag dtype. (round-6 verbatim)
// ---------------------------------------------------------------------------
__global__ __launch_bounds__(256) void k_out2(
    const float* __restrict__ u1o, const float* __restrict__ ow2,
    const float* __restrict__ ob2, const int* __restrict__ flag,
    void* __restrict__ out) {
  __shared__ float ul[2 * HH];
  const int t = threadIdx.x;
  const int r0 = blockIdx.x * 2;
  const int r = t >> 7, c = t & 127;
  ul[t] = u1o[(size_t)r0 * HH + t];
  ul[256 + t] = u1o[(size_t)r0 * HH + 256 + t];
  __syncthreads();
  float acc = 0.f;
  const float* ur = &ul[r * HH];
  #pragma unroll 8
  for (int k = 0; k < HH; k++) acc = fmaf(ur[k], ow2[k * DD + c], acc);
  float v = acc + ob2[c];
  size_t o = (size_t)(r0 + r) * DD + c;
  if (*flag) ((u16*)out)[o] = f2bf(v);
  else ((float*)out)[o] = v;
}

extern "C" void kernel_launch(void* const* d_in, const int* in_sizes, int n_in,
                              void* d_out, int out_size, void* d_ws,
                              size_t ws_size, hipStream_t stream) {
  const int wb = (n_in >= 17 && in_sizes[2] == 2048) ? 3 : 2;

  char* ws = (char*)d_ws;
  int* flag    = (int*)ws;                                 // @0
  float* xbuf  = (float*)(ws + 4096);                      // 1 MB
  float* hsum  = (float*)(ws + 4096 + 1048576);            // 2 MB (also u1/u1o)
  float* canon = (float*)(ws + 4096 + 1048576 + 2097152);  // 3.23 MB

  WPtrs wp;
  for (int i = 0; i < 14; i++) wp.p[i] = d_in[wb + i];

  // canon float offsets (round-6 verbatim)
  const int MW1 = 0, MB1 = 147456, MW2 = 148224, MB2 = 344832, UW1 = 345600,
            UB1 = 640512, UW2 = 641280, UB2 = 739584, LNG = 739968,
            LNB = 740352, OW1 = 740736, OB1 = 773504, OW2 = 773760,
            OB2 = 806528;
  (void)UB1;

  k_detect<<<1, 256, 0, stream>>>((const u16*)d_in[0], flag, d_out, out_size);
  k_cvtw<float><<<512, 256, 0, stream>>>(wp, flag, canon, 0);
  k_cvtw<u16><<<512, 256, 0, stream>>>(wp, flag, canon, 1);
  k_cvtn<float><<<256, 256, 0, stream>>>((const float*)d_in[0], flag, xbuf, 0);
  k_cvtn<u16><<<256, 256, 0, stream>>>((const u16*)d_in[0], flag, xbuf, 1);
  // NEW: pre-transpose W1e into canon's dead MW1 rows-128..191 slot (after cvtw)
  k_prep<float><<<3, 256, 0, stream>>>((const float*)d_in[wb + 0], flag, 0,
                                       canon + MW1);
  k_prep<u16><<<3, 256, 0, stream>>>((const u16*)d_in[wb + 0], flag, 1,
                                     canon + MW1);
  // fuse AFTER cvtw (overwrites canon MW2/MB2 slots, reading typed globals)
  k_fuse<float><<<771, 256, 0, stream>>>(
      (const float*)d_in[wb + 2], (const float*)d_in[wb + 3],
      (const float*)d_in[wb + 4], (const float*)d_in[wb + 5], flag, 0,
      canon + MW2, canon + MB2);
  k_fuse<u16><<<771, 256, 0, stream>>>(
      (const u16*)d_in[wb + 2], (const u16*)d_in[wb + 3],
      (const u16*)d_in[wb + 4], (const u16*)d_in[wb + 5], flag, 1,
      canon + MW2, canon + MB2);

  for (int l = 0; l < 3; l++) {
    const float* w1C = canon + MW1 + l * 49152;
    const float* b1C = canon + MB1 + l * 256;
    k_edge<float><<<BN, 256, 0, stream>>>((const float*)d_in[1], flag, 0, xbuf,
                                          w1C, b1C, hsum);
    k_edge<u16><<<BN, 256, 0, stream>>>((const u16*)d_in[1], flag, 1, xbuf,
                                        w1C, b1C, hsum);
    k_mlp1<<<512, 256, 0, stream>>>(xbuf, hsum, canon + UW1 + l * 98304,
                                    canon + MW2 + l * 65536,
                                    canon + MB2 + l * 256);
    k_mlp2ln<<<1024, 256, 0, stream>>>(hsum, xbuf, canon + UW2 + l * 32768,
                                       canon + UB2 + l * 128,
                                       canon + LNG + l * 128,
                                       canon + LNB + l * 128);
  }
  k_out1<<<512, 256, 0, stream>>>(xbuf, hsum, canon + OW1, canon + OB1);
  k_out2<<<1024, 256, 0, stream>>>(hsum, canon + OW2, canon + OB2, flag,
                                   d_out);
}